// Round 5
// baseline (12030.432 us; speedup 1.0000x reference)
//
#include <hip/hip_runtime.h>

// ---------------------------------------------------------------------------
// LSTM encoder: B=64, S=512, E=256, H=512, gates 4H=2048 (i,f,g,o)
// R4/R5 structure inversion: W_hh distributed across 64 blocks (32 gate-rows
// each, register-resident B-fragments). Per step each block stages the shared
// 64KB h [64b x 512k] into LDS, computes G[64b x 32rows] via 16x16x32 f16
// MFMA, updates c/h for its 8 units (c in registers), writes its 1KB h-slice,
// crosses a device-scope grid barrier. Bytes/CU/step: 2MB -> 64KB.
//   P  (prep): pack Wd [blk][row=u*4+g][k] f16, Wip for xg, bsum, zero H0/H1/
//              cstate/barrier counters.
//   Q  (xg):   unchanged from R3 (verified): xg[tau][j][4] f16.
//   R  (rec2): 64 blocks x 512 thr, grid barrier per step (double-buffered H).
// R5 fix: __hip_atomic_fence not in this ROCm -> __threadfence(); release/
// acquire fences executed by ALL threads (thread-0-only fence doesn't order
// other threads' stores; matches ROCm coop-groups grid sync pattern).
// Fallback (ws too small): naive all-f32 kernel.
// ---------------------------------------------------------------------------

typedef _Float16 half2_t __attribute__((ext_vector_type(2)));
typedef _Float16 half8 __attribute__((ext_vector_type(8)));
typedef float f32x4 __attribute__((ext_vector_type(4)));
typedef short short4_t __attribute__((ext_vector_type(4)));

__device__ __forceinline__ float dot2h(int w, int h, float c) {
#if __has_builtin(__builtin_amdgcn_fdot2)
  return __builtin_amdgcn_fdot2(__builtin_bit_cast(half2_t, w),
                                __builtin_bit_cast(half2_t, h), c, false);
#else
  half2_t a = __builtin_bit_cast(half2_t, w);
  half2_t b = __builtin_bit_cast(half2_t, h);
  return fmaf((float)a[1], (float)b[1], fmaf((float)a[0], (float)b[0], c));
#endif
}

__device__ __forceinline__ float sigm(float x) { return 1.0f / (1.0f + __expf(-x)); }
__device__ __forceinline__ float tanh_(float x) { return 1.0f - 2.0f / (__expf(2.0f * x) + 1.0f); }

// ---------------------------------------------------------------------------
// P: Wd[((blk*32 + u*4+g))*512 + k] = W_hh[(g*512 + blk*8+u)*512 + k]  (f16)
//    Wip[(k2*512+j)*8+g*2+kk] = W_ih[(g*512+j)*256+2*k2+kk] (k2<128)
//    bsum[j*4+g] = b_ih + b_hh ; H0/H1, cstate, cnt[64] zeroed.
// ---------------------------------------------------------------------------
__global__ __launch_bounds__(256) void prep_kernel(
    const float* __restrict__ W_hh, const float* __restrict__ W_ih,
    const float* __restrict__ b_ih, const float* __restrict__ b_hh,
    _Float16* __restrict__ Wd, _Float16* __restrict__ Wip,
    float* __restrict__ bsum, _Float16* __restrict__ Hz,  // H0 (H1 contiguous)
    float* __restrict__ cstate, unsigned* __restrict__ cnt) {
  const int S0 = 1048576;            // Wd elements
  const int S1 = S0 + 65536;         // Wip idx (j,k2)
  const int S2 = S1 + 2048;          // bsum
  const int S3 = S2 + 65536;         // H0+H1 halves
  const int S4 = S3 + 32768;         // cstate floats
  const int S5 = S4 + 64;            // counters
  for (int idx = blockIdx.x * blockDim.x + threadIdx.x; idx < S5;
       idx += gridDim.x * blockDim.x) {
    if (idx < S0) {
      int k = idx & 511, row = (idx >> 9) & 31, blk = idx >> 14;
      int u = row >> 2, g = row & 3;
      Wd[idx] = (_Float16)W_hh[(size_t)(g * 512 + blk * 8 + u) * 512 + k];
    } else if (idx < S1) {
      int e = idx - S0;
      int j = e & 511, k2 = e >> 9;  // k2 in [0,128)
#pragma unroll
      for (int g = 0; g < 4; ++g) {
        Wip[(size_t)(k2 * 512 + j) * 8 + g * 2 + 0] =
            (_Float16)W_ih[(size_t)(g * 512 + j) * 256 + 2 * k2 + 0];
        Wip[(size_t)(k2 * 512 + j) * 8 + g * 2 + 1] =
            (_Float16)W_ih[(size_t)(g * 512 + j) * 256 + 2 * k2 + 1];
      }
    } else if (idx < S2) {
      int e = idx - S1;
      int j = e >> 2, g = e & 3;
      bsum[e] = b_ih[g * 512 + j] + b_hh[g * 512 + j];
    } else if (idx < S3) {
      Hz[idx - S2] = (_Float16)0.0f;
    } else if (idx < S4) {
      cstate[idx - S3] = 0.0f;
    } else {
      cnt[idx - S4] = 0u;
    }
  }
}

// ---------------------------------------------------------------------------
// Q: x_gates (unchanged from R3, verified). 8 tokens/block, 512 thr.
// ---------------------------------------------------------------------------
__global__ __launch_bounds__(512, 1) void xg_kernel(
    const int* __restrict__ seq, const float* __restrict__ emb,
    const _Float16* __restrict__ Wip, const float* __restrict__ bsum,
    _Float16* __restrict__ xg, int t0, int Tc) {
  __shared__ int toks[8];
  __shared__ __align__(16) _Float16 el[128 * 16];  // [k2][tok][2]
  const int tid = threadIdx.x;
  const int tau0 = blockIdx.x * 8;

  if (tid < 8) {
    int tau = tau0 + tid;
    int b = tau / Tc, tl = tau - b * Tc;
    toks[tid] = seq[b * 512 + t0 + tl];
  }
  __syncthreads();
  for (int e = tid; e < 2048; e += 512) {
    int i = e >> 8, k = e & 255;
    el[((k >> 1) * 8 + i) * 2 + (k & 1)] = (_Float16)emb[(size_t)toks[i] * 256 + k];
  }
  __syncthreads();

  const int j = tid;
  float4 bs = *(const float4*)&bsum[j * 4];
  float acc[8][4];
#pragma unroll
  for (int i = 0; i < 8; ++i) {
    acc[i][0] = bs.x; acc[i][1] = bs.y; acc[i][2] = bs.z; acc[i][3] = bs.w;
  }
  const _Float16* wp = Wip + (size_t)j * 8;
#pragma unroll 2
  for (int k2 = 0; k2 < 128; ++k2) {
    int4 w = *(const int4*)(wp + (size_t)k2 * 4096);
    int4 e0 = *(const int4*)(el + k2 * 16);
    int4 e1 = *(const int4*)(el + k2 * 16 + 8);
    acc[0][0] = dot2h(w.x, e0.x, acc[0][0]); acc[0][1] = dot2h(w.y, e0.x, acc[0][1]);
    acc[0][2] = dot2h(w.z, e0.x, acc[0][2]); acc[0][3] = dot2h(w.w, e0.x, acc[0][3]);
    acc[1][0] = dot2h(w.x, e0.y, acc[1][0]); acc[1][1] = dot2h(w.y, e0.y, acc[1][1]);
    acc[1][2] = dot2h(w.z, e0.y, acc[1][2]); acc[1][3] = dot2h(w.w, e0.y, acc[1][3]);
    acc[2][0] = dot2h(w.x, e0.z, acc[2][0]); acc[2][1] = dot2h(w.y, e0.z, acc[2][1]);
    acc[2][2] = dot2h(w.z, e0.z, acc[2][2]); acc[2][3] = dot2h(w.w, e0.z, acc[2][3]);
    acc[3][0] = dot2h(w.x, e0.w, acc[3][0]); acc[3][1] = dot2h(w.y, e0.w, acc[3][1]);
    acc[3][2] = dot2h(w.z, e0.w, acc[3][2]); acc[3][3] = dot2h(w.w, e0.w, acc[3][3]);
    acc[4][0] = dot2h(w.x, e1.x, acc[4][0]); acc[4][1] = dot2h(w.y, e1.x, acc[4][1]);
    acc[4][2] = dot2h(w.z, e1.x, acc[4][2]); acc[4][3] = dot2h(w.w, e1.x, acc[4][3]);
    acc[5][0] = dot2h(w.x, e1.y, acc[5][0]); acc[5][1] = dot2h(w.y, e1.y, acc[5][1]);
    acc[5][2] = dot2h(w.z, e1.y, acc[5][2]); acc[5][3] = dot2h(w.w, e1.y, acc[5][3]);
    acc[6][0] = dot2h(w.x, e1.z, acc[6][0]); acc[6][1] = dot2h(w.y, e1.z, acc[6][1]);
    acc[6][2] = dot2h(w.z, e1.z, acc[6][2]); acc[6][3] = dot2h(w.w, e1.z, acc[6][3]);
    acc[7][0] = dot2h(w.x, e1.w, acc[7][0]); acc[7][1] = dot2h(w.y, e1.w, acc[7][1]);
    acc[7][2] = dot2h(w.z, e1.w, acc[7][2]); acc[7][3] = dot2h(w.w, e1.w, acc[7][3]);
  }
#pragma unroll
  for (int i = 0; i < 8; ++i) {
    short4_t sv;
    sv[0] = __builtin_bit_cast(short, (_Float16)acc[i][0]);
    sv[1] = __builtin_bit_cast(short, (_Float16)acc[i][1]);
    sv[2] = __builtin_bit_cast(short, (_Float16)acc[i][2]);
    sv[3] = __builtin_bit_cast(short, (_Float16)acc[i][3]);
    *(short4_t*)(xg + ((size_t)(tau0 + i) * 512 + j) * 4) = sv;
  }
}

// ---------------------------------------------------------------------------
// Grid barrier: 64 blocks, monotonic per-chunk counter.  ALL threads fence
// (release before / acquire after) so every thread's global stores are
// agent-visible and every thread's subsequent loads see remote stores.
// Safe: grid=64 <= 256 CUs (all blocks co-resident).
// ---------------------------------------------------------------------------
__device__ __forceinline__ void grid_barrier(unsigned* cnt, unsigned target) {
  __threadfence();   // release: order this thread's prior global writes
  __syncthreads();   // all threads of block have fenced
  if (threadIdx.x == 0) {
    __hip_atomic_fetch_add(cnt, 1u, __ATOMIC_RELAXED, __HIP_MEMORY_SCOPE_AGENT);
    while (__hip_atomic_load(cnt, __ATOMIC_RELAXED, __HIP_MEMORY_SCOPE_AGENT) <
           target) {
      __builtin_amdgcn_s_sleep(1);
    }
  }
  __syncthreads();
  __threadfence();   // acquire: invalidate stale cached lines before re-read
}

// ---------------------------------------------------------------------------
// R: rec2. grid=64 blocks x 512 thr. Block blk owns units [blk*8, blk*8+8),
// i.e. Wd rows [blk*32, blk*32+32) (row = u*4+g). 8 waves = 4 Mtiles(batch)
// x 2 Ntiles(rows). B-frags register-resident. H double-buffered in global,
// staged to LDS per step with XOR swizzle on 16B granules.
// MFMA layouts (m89/m91): A row=l&15,k=(l>>4)*8+j; B col=l&15 same k;
// D n=l&15, m=(l>>4)*4+reg.  G = h @ Wd^T : m=batch, n=row.
// ---------------------------------------------------------------------------
__global__ __launch_bounds__(512, 1) void rec2_kernel(
    const _Float16* __restrict__ xg, const _Float16* __restrict__ Wd,
    _Float16* __restrict__ H0, _Float16* __restrict__ H1,
    float* __restrict__ cstate, unsigned* __restrict__ cnt,
    float* __restrict__ out, int t0, int Tc) {
  __shared__ __align__(16) _Float16 Hl[64 * 512];  // 64 KB, swizzled
  __shared__ float Gl[32 * 68];                    // rows x batch, pad 68

  const int blk = blockIdx.x;
  const int tid = threadIdx.x;
  const int l = tid & 63, w = tid >> 6;
  const int mt = w >> 1, nt = w & 1;
  const int arow = mt * 16 + (l & 15);  // batch row for A-frag
  const int koct = l >> 4;              // 0..3

  // pointwise ownership: batch pb, unit pu
  const int pb = tid >> 3, pu = tid & 7;
  const int jglob = blk * 8 + pu;

  // B-fragment preload: 16 KB/wave -> 64 VGPR/lane, loaded once.
  half8 Bf[16];
  {
    const _Float16* wrow =
        Wd + ((size_t)blk * 32 + nt * 16 + (l & 15)) * 512 + koct * 8;
#pragma unroll
    for (int kk = 0; kk < 16; ++kk) Bf[kk] = *(const half8*)(wrow + kk * 32);
  }

  float c = cstate[pb * 512 + jglob];

  for (int tl = 0; tl < Tc; ++tl) {
    const int t = t0 + tl;
    const _Float16* Hc = (t & 1) ? H1 : H0;
    _Float16* Hn = (t & 1) ? H0 : H1;

    // ---- stage H (64 KB) to LDS, swizzled: halfidx(b,k8)=b*512+((k8^(b&7))<<3)
#pragma unroll
    for (int c8 = 0; c8 < 8; ++c8) {
      int ch = c8 * 512 + tid;  // 16B chunk id, 4096 total
      int bb = ch >> 6, k8 = ch & 63;
      int4 v = *(const int4*)(Hc + ch * 8);
      *(int4*)&Hl[bb * 512 + ((k8 ^ (bb & 7)) << 3)] = v;
    }
    // xg for this thread's (pb,pu): 4 gates contiguous (8B), hides under stage
    short4_t xs = *(const short4_t*)(xg + ((size_t)(pb * Tc + tl) * 512 + jglob) * 4);
    __syncthreads();

    // ---- MFMA: G[64b x 32rows] slab, this wave's 16x16 tile
    f32x4 acc = {0.f, 0.f, 0.f, 0.f};
#pragma unroll
    for (int kk = 0; kk < 16; ++kk) {
      int k8 = kk * 4 + koct;
      half8 A = *(const half8*)&Hl[arow * 512 + ((k8 ^ (arow & 7)) << 3)];
      acc = __builtin_amdgcn_mfma_f32_16x16x32_f16(A, Bf[kk], acc, 0, 0, 0);
    }
    // D: n(row)=l&15, m(batch)=(l>>4)*4+reg -> Gl[row*68 + batch]
    *(f32x4*)&Gl[(nt * 16 + (l & 15)) * 68 + mt * 16 + koct * 4] = acc;
    __syncthreads();

    // ---- pointwise for (pb, pu)
    float g0 = (float)__builtin_bit_cast(_Float16, (short)xs[0]) + Gl[(pu * 4 + 0) * 68 + pb];
    float g1 = (float)__builtin_bit_cast(_Float16, (short)xs[1]) + Gl[(pu * 4 + 1) * 68 + pb];
    float g2 = (float)__builtin_bit_cast(_Float16, (short)xs[2]) + Gl[(pu * 4 + 2) * 68 + pb];
    float g3 = (float)__builtin_bit_cast(_Float16, (short)xs[3]) + Gl[(pu * 4 + 3) * 68 + pb];
    float ig = sigm(g0), fg = sigm(g1), gg = tanh_(g2), og = sigm(g3);
    c = fg * c + ig * gg;
    float hn = og * tanh_(c);
    Hn[pb * 512 + jglob] = (_Float16)hn;
    if (t == 511) {
      out[pb * 512 + jglob] = hn;
      out[32768 + pb * 512 + jglob] = c;
    }

    // ---- grid barrier (skip after last local step; stream order covers it)
    if (tl != Tc - 1) grid_barrier(cnt, 64u * (unsigned)(tl + 1));
  }
  cstate[pb * 512 + jglob] = c;
}

// ---------------------------------------------------------------------------
// Fallback: all-f32 straight from inputs (only if ws_size is tiny).
// ---------------------------------------------------------------------------
__global__ __launch_bounds__(512, 1) void naive_kernel(
    const int* __restrict__ seq, const float* __restrict__ emb,
    const float* __restrict__ W_ih, const float* __restrict__ W_hh,
    const float* __restrict__ b_ih, const float* __restrict__ b_hh,
    float* __restrict__ out) {
  __shared__ float hl[512];
  const int b = blockIdx.x, j = threadIdx.x;
  hl[j] = 0.f;
  float c = 0.f;
  __syncthreads();
  for (int t = 0; t < 512; ++t) {
    int tok = seq[b * 512 + t];
    float A[4];
#pragma unroll
    for (int g = 0; g < 4; ++g) A[g] = b_ih[g * 512 + j] + b_hh[g * 512 + j];
    for (int k = 0; k < 256; ++k) {
      float e = emb[(size_t)tok * 256 + k];
#pragma unroll
      for (int g = 0; g < 4; ++g) A[g] += e * W_ih[(size_t)(g * 512 + j) * 256 + k];
    }
    for (int k = 0; k < 512; ++k) {
      float h = hl[k];
#pragma unroll
      for (int g = 0; g < 4; ++g) A[g] += h * W_hh[(size_t)(g * 512 + j) * 512 + k];
    }
    __syncthreads();
    float ig = sigm(A[0]), fg = sigm(A[1]), gg = tanh_(A[2]), og = sigm(A[3]);
    c = fg * c + ig * gg;
    float hn = og * tanh_(c);
    hl[j] = hn;
    __syncthreads();
    if (t == 511) {
      out[b * 512 + j] = hn;
      out[32768 + b * 512 + j] = c;
    }
  }
}

// ---------------------------------------------------------------------------
extern "C" void kernel_launch(void* const* d_in, const int* in_sizes, int n_in,
                              void* d_out, int out_size, void* d_ws, size_t ws_size,
                              hipStream_t stream) {
  const int* seq = (const int*)d_in[0];
  const float* emb = (const float*)d_in[1];
  const float* W_ih = (const float*)d_in[2];
  const float* W_hh = (const float*)d_in[3];
  const float* b_ih = (const float*)d_in[4];
  const float* b_hh = (const float*)d_in[5];
  float* out = (float*)d_out;

  // workspace layout
  char* w = (char*)d_ws;
  _Float16* Wd = (_Float16*)(w + 0);            // 2,097,152 B
  _Float16* Wip = (_Float16*)(w + 2097152);     // 1,048,576 B
  float* bsum = (float*)(w + 3145728);          //     8,192 B
  _Float16* H0 = (_Float16*)(w + 3153920);      //    65,536 B
  _Float16* H1 = (_Float16*)(w + 3219456);      //    65,536 B
  float* cstate = (float*)(w + 3284992);        //   131,072 B
  unsigned* cnt = (unsigned*)(w + 3416064);     //       256 B (64 slots)
  _Float16* xgbuf = (_Float16*)(w + 3416320);   // Tc*262,144 B
  const size_t base = 3416320;

  int Tc = 0;
  const int cands[7] = {512, 256, 128, 64, 32, 16, 8};
  for (int ci = 0; ci < 7; ++ci) {
    if (base + (size_t)cands[ci] * 262144 <= ws_size) { Tc = cands[ci]; break; }
  }

  if (Tc == 0) {
    naive_kernel<<<64, 512, 0, stream>>>(seq, emb, W_ih, W_hh, b_ih, b_hh, out);
    return;
  }

  prep_kernel<<<1024, 256, 0, stream>>>(W_hh, W_ih, b_ih, b_hh, Wd, Wip, bsum,
                                        H0, cstate, cnt);
  for (int t0 = 0; t0 < 512; t0 += Tc) {
    xg_kernel<<<8 * Tc, 512, 0, stream>>>(seq, emb, Wip, bsum, xgbuf, t0, Tc);
    rec2_kernel<<<64, 512, 0, stream>>>(xgbuf, Wd, H0, H1, cstate,
                                        cnt + (t0 / Tc), out, t0, Tc);
  }
}

// Round 7
// 2365.245 us; speedup vs baseline: 5.0863x; 5.0863x over previous
//
#include <hip/hip_runtime.h>

// ---------------------------------------------------------------------------
// LSTM encoder: B=64, S=512, E=256, H=512, gates 4H=2048 (i,f,g,o)
// R6: W_hh register-resident across 64 blocks (structure verified in R5).
// Inter-step h exchange is now FENCE-FREE: h crosses XCDs through the L3
// coherence point only (sc0 sc1 write-through stores + sc0 sc1 bypass loads).
// R5's __threadfence (agent fence = full L2 writeback+invalidate per step)
// was the 22.7us/step wall: VALUBusy 0.4%, FETCH_SIZE 74->264MB.
//   P  (prep): pack Wd [blk][row][k] f16, Wip, bsum, zero H0/H1/c/cnt.
//   Q  (xg):   x_gates precompute (verified R3/R5), f16 packed [tau][j][4].
//   R  (rec2): 64 blocks x 512 thr; per step: coherent H load -> LDS ->
//              MFMA G[64x32] -> pointwise -> packed coherent h store ->
//              relaxed-atomic counter barrier (no fences).
// Coherence audit (R7 resubmit): prep's plain zero-stores to cnt/H0 are
// visible to rec2's bypassing atomics via end-of-kernel L2 writeback
// (kernel-boundary release). Double-buffer WAR safe via barrier ordering.
// Fallback (ws too small): naive all-f32 kernel.
// ---------------------------------------------------------------------------

typedef _Float16 half2_t __attribute__((ext_vector_type(2)));
typedef _Float16 half8 __attribute__((ext_vector_type(8)));
typedef float f32x4 __attribute__((ext_vector_type(4)));
typedef short short4_t __attribute__((ext_vector_type(4)));

__device__ __forceinline__ float dot2h(int w, int h, float c) {
#if __has_builtin(__builtin_amdgcn_fdot2)
  return __builtin_amdgcn_fdot2(__builtin_bit_cast(half2_t, w),
                                __builtin_bit_cast(half2_t, h), c, false);
#else
  half2_t a = __builtin_bit_cast(half2_t, w);
  half2_t b = __builtin_bit_cast(half2_t, h);
  return fmaf((float)a[1], (float)b[1], fmaf((float)a[0], (float)b[0], c));
#endif
}

__device__ __forceinline__ float sigm(float x) { return 1.0f / (1.0f + __expf(-x)); }
__device__ __forceinline__ float tanh_(float x) { return 1.0f - 2.0f / (__expf(2.0f * x) + 1.0f); }

// Coherent 16B load: bypass L1+L2, read from L3 (device coherence point).
__device__ __forceinline__ int4 ld_cohere16(const void* p) {
  int4 v;
  asm volatile("global_load_dwordx4 %0, %1, off sc0 sc1"
               : "=v"(v) : "v"(p) : "memory");
  return v;
}

// ---------------------------------------------------------------------------
// P: Wd[((blk*32 + u*4+g))*512 + k] = W_hh[(g*512 + blk*8+u)*512 + k]  (f16)
//    Wip[(k2*512+j)*8+g*2+kk] = W_ih[(g*512+j)*256+2*k2+kk] (k2<128)
//    bsum[j*4+g] = b_ih + b_hh ; H0/H1, cstate, cnt[64] zeroed.
// ---------------------------------------------------------------------------
__global__ __launch_bounds__(256) void prep_kernel(
    const float* __restrict__ W_hh, const float* __restrict__ W_ih,
    const float* __restrict__ b_ih, const float* __restrict__ b_hh,
    _Float16* __restrict__ Wd, _Float16* __restrict__ Wip,
    float* __restrict__ bsum, _Float16* __restrict__ Hz,  // H0 (H1 contiguous)
    float* __restrict__ cstate, unsigned* __restrict__ cnt) {
  const int S0 = 1048576;            // Wd elements
  const int S1 = S0 + 65536;         // Wip idx (j,k2)
  const int S2 = S1 + 2048;          // bsum
  const int S3 = S2 + 65536;         // H0+H1 halves
  const int S4 = S3 + 32768;         // cstate floats
  const int S5 = S4 + 64;            // counters
  for (int idx = blockIdx.x * blockDim.x + threadIdx.x; idx < S5;
       idx += gridDim.x * blockDim.x) {
    if (idx < S0) {
      int k = idx & 511, row = (idx >> 9) & 31, blk = idx >> 14;
      int u = row >> 2, g = row & 3;
      Wd[idx] = (_Float16)W_hh[(size_t)(g * 512 + blk * 8 + u) * 512 + k];
    } else if (idx < S1) {
      int e = idx - S0;
      int j = e & 511, k2 = e >> 9;  // k2 in [0,128)
#pragma unroll
      for (int g = 0; g < 4; ++g) {
        Wip[(size_t)(k2 * 512 + j) * 8 + g * 2 + 0] =
            (_Float16)W_ih[(size_t)(g * 512 + j) * 256 + 2 * k2 + 0];
        Wip[(size_t)(k2 * 512 + j) * 8 + g * 2 + 1] =
            (_Float16)W_ih[(size_t)(g * 512 + j) * 256 + 2 * k2 + 1];
      }
    } else if (idx < S2) {
      int e = idx - S1;
      int j = e >> 2, g = e & 3;
      bsum[e] = b_ih[g * 512 + j] + b_hh[g * 512 + j];
    } else if (idx < S3) {
      Hz[idx - S2] = (_Float16)0.0f;
    } else if (idx < S4) {
      cstate[idx - S3] = 0.0f;
    } else {
      cnt[idx - S4] = 0u;
    }
  }
}

// ---------------------------------------------------------------------------
// Q: x_gates (verified). 8 tokens/block, 512 thr.
// ---------------------------------------------------------------------------
__global__ __launch_bounds__(512, 1) void xg_kernel(
    const int* __restrict__ seq, const float* __restrict__ emb,
    const _Float16* __restrict__ Wip, const float* __restrict__ bsum,
    _Float16* __restrict__ xg, int t0, int Tc) {
  __shared__ int toks[8];
  __shared__ __align__(16) _Float16 el[128 * 16];  // [k2][tok][2]
  const int tid = threadIdx.x;
  const int tau0 = blockIdx.x * 8;

  if (tid < 8) {
    int tau = tau0 + tid;
    int b = tau / Tc, tl = tau - b * Tc;
    toks[tid] = seq[b * 512 + t0 + tl];
  }
  __syncthreads();
  for (int e = tid; e < 2048; e += 512) {
    int i = e >> 8, k = e & 255;
    el[((k >> 1) * 8 + i) * 2 + (k & 1)] = (_Float16)emb[(size_t)toks[i] * 256 + k];
  }
  __syncthreads();

  const int j = tid;
  float4 bs = *(const float4*)&bsum[j * 4];
  float acc[8][4];
#pragma unroll
  for (int i = 0; i < 8; ++i) {
    acc[i][0] = bs.x; acc[i][1] = bs.y; acc[i][2] = bs.z; acc[i][3] = bs.w;
  }
  const _Float16* wp = Wip + (size_t)j * 8;
#pragma unroll 2
  for (int k2 = 0; k2 < 128; ++k2) {
    int4 w = *(const int4*)(wp + (size_t)k2 * 4096);
    int4 e0 = *(const int4*)(el + k2 * 16);
    int4 e1 = *(const int4*)(el + k2 * 16 + 8);
    acc[0][0] = dot2h(w.x, e0.x, acc[0][0]); acc[0][1] = dot2h(w.y, e0.x, acc[0][1]);
    acc[0][2] = dot2h(w.z, e0.x, acc[0][2]); acc[0][3] = dot2h(w.w, e0.x, acc[0][3]);
    acc[1][0] = dot2h(w.x, e0.y, acc[1][0]); acc[1][1] = dot2h(w.y, e0.y, acc[1][1]);
    acc[1][2] = dot2h(w.z, e0.y, acc[1][2]); acc[1][3] = dot2h(w.w, e0.y, acc[1][3]);
    acc[2][0] = dot2h(w.x, e0.z, acc[2][0]); acc[2][1] = dot2h(w.y, e0.z, acc[2][1]);
    acc[2][2] = dot2h(w.z, e0.z, acc[2][2]); acc[2][3] = dot2h(w.w, e0.z, acc[2][3]);
    acc[3][0] = dot2h(w.x, e0.w, acc[3][0]); acc[3][1] = dot2h(w.y, e0.w, acc[3][1]);
    acc[3][2] = dot2h(w.z, e0.w, acc[3][2]); acc[3][3] = dot2h(w.w, e0.w, acc[3][3]);
    acc[4][0] = dot2h(w.x, e1.x, acc[4][0]); acc[4][1] = dot2h(w.y, e1.x, acc[4][1]);
    acc[4][2] = dot2h(w.z, e1.x, acc[4][2]); acc[4][3] = dot2h(w.w, e1.x, acc[4][3]);
    acc[5][0] = dot2h(w.x, e1.y, acc[5][0]); acc[5][1] = dot2h(w.y, e1.y, acc[5][1]);
    acc[5][2] = dot2h(w.z, e1.y, acc[5][2]); acc[5][3] = dot2h(w.w, e1.y, acc[5][3]);
    acc[6][0] = dot2h(w.x, e1.z, acc[6][0]); acc[6][1] = dot2h(w.y, e1.z, acc[6][1]);
    acc[6][2] = dot2h(w.z, e1.z, acc[6][2]); acc[6][3] = dot2h(w.w, e1.z, acc[6][3]);
    acc[7][0] = dot2h(w.x, e1.w, acc[7][0]); acc[7][1] = dot2h(w.y, e1.w, acc[7][1]);
    acc[7][2] = dot2h(w.z, e1.w, acc[7][2]); acc[7][3] = dot2h(w.w, e1.w, acc[7][3]);
  }
#pragma unroll
  for (int i = 0; i < 8; ++i) {
    short4_t sv;
    sv[0] = __builtin_bit_cast(short, (_Float16)acc[i][0]);
    sv[1] = __builtin_bit_cast(short, (_Float16)acc[i][1]);
    sv[2] = __builtin_bit_cast(short, (_Float16)acc[i][2]);
    sv[3] = __builtin_bit_cast(short, (_Float16)acc[i][3]);
    *(short4_t*)(xg + ((size_t)(tau0 + i) * 512 + j) * 4) = sv;
  }
}

// ---------------------------------------------------------------------------
// R: rec2. grid=64 blocks x 512 thr. Block blk owns units [blk*8, blk*8+8).
// Per step: coherent H load (sc0sc1, L3) -> LDS swizzled -> 16 MFMA ->
// Gl -> pointwise -> packed 4B coherent h store -> vmcnt(0) ->
// relaxed-atomic counter barrier (NO cache-flushing fences).
// Safety: (a) stores acked at coherence point before counter inc (vmcnt0);
// (b) double-buffer WAR safe: a block's inc follows its loads, so no block
// can overwrite a buffer another block is still reading.
// ---------------------------------------------------------------------------
__global__ __launch_bounds__(512, 1) void rec2_kernel(
    const _Float16* __restrict__ xg, const _Float16* __restrict__ Wd,
    _Float16* __restrict__ H0, _Float16* __restrict__ H1,
    float* __restrict__ cstate, unsigned* __restrict__ cnt,
    float* __restrict__ out, int t0, int Tc) {
  __shared__ __align__(16) _Float16 Hl[64 * 512];  // 64 KB, swizzled
  __shared__ float Gl[32 * 68];                    // rows x batch, pad 68

  const int blk = blockIdx.x;
  const int tid = threadIdx.x;
  const int l = tid & 63, w = tid >> 6;
  const int mt = w >> 1, nt = w & 1;
  const int arow = mt * 16 + (l & 15);  // batch row for A-frag
  const int koct = l >> 4;              // 0..3

  // pointwise ownership: batch pb, unit pu
  const int pb = tid >> 3, pu = tid & 7;
  const int jglob = blk * 8 + pu;

  // B-fragment preload: 16 KB/wave -> 64 VGPR/lane, loaded once.
  half8 Bf[16];
  {
    const _Float16* wrow =
        Wd + ((size_t)blk * 32 + nt * 16 + (l & 15)) * 512 + koct * 8;
#pragma unroll
    for (int kk = 0; kk < 16; ++kk) Bf[kk] = *(const half8*)(wrow + kk * 32);
  }

  float c = cstate[pb * 512 + jglob];

  for (int tl = 0; tl < Tc; ++tl) {
    const int t = t0 + tl;
    const _Float16* Hc = (t & 1) ? H1 : H0;
    _Float16* Hn = (t & 1) ? H0 : H1;

    // xg prefetch (plain load; L2-cached, read-only -> no coherence needed)
    short4_t xs = *(const short4_t*)(xg + ((size_t)(pb * Tc + tl) * 512 + jglob) * 4);

    // ---- coherent H load (8 x 16B per thread, pipelined) -> LDS swizzled
    int4 hv[8];
#pragma unroll
    for (int c8 = 0; c8 < 8; ++c8) {
      int ch = c8 * 512 + tid;  // 16B chunk id, 4096 total
      hv[c8] = ld_cohere16(Hc + ch * 8);
    }
    asm volatile("s_waitcnt vmcnt(0)" ::: "memory");
    __builtin_amdgcn_sched_barrier(0);
#pragma unroll
    for (int c8 = 0; c8 < 8; ++c8) {
      int ch = c8 * 512 + tid;
      int bb = ch >> 6, k8 = ch & 63;
      *(int4*)&Hl[bb * 512 + ((k8 ^ (bb & 7)) << 3)] = hv[c8];
    }
    __syncthreads();

    // ---- MFMA: G[64b x 32rows] slab, this wave's 16x16 tile
    f32x4 acc = {0.f, 0.f, 0.f, 0.f};
#pragma unroll
    for (int kk = 0; kk < 16; ++kk) {
      int k8 = kk * 4 + koct;
      half8 A = *(const half8*)&Hl[arow * 512 + ((k8 ^ (arow & 7)) << 3)];
      acc = __builtin_amdgcn_mfma_f32_16x16x32_f16(A, Bf[kk], acc, 0, 0, 0);
    }
    // D: n(row)=l&15, m(batch)=(l>>4)*4+reg -> Gl[row*68 + batch]
    *(f32x4*)&Gl[(nt * 16 + (l & 15)) * 68 + mt * 16 + koct * 4] = acc;
    __syncthreads();

    // ---- pointwise for (pb, pu)
    float g0 = (float)__builtin_bit_cast(_Float16, (short)xs[0]) + Gl[(pu * 4 + 0) * 68 + pb];
    float g1 = (float)__builtin_bit_cast(_Float16, (short)xs[1]) + Gl[(pu * 4 + 1) * 68 + pb];
    float g2 = (float)__builtin_bit_cast(_Float16, (short)xs[2]) + Gl[(pu * 4 + 2) * 68 + pb];
    float g3 = (float)__builtin_bit_cast(_Float16, (short)xs[3]) + Gl[(pu * 4 + 3) * 68 + pb];
    float ig = sigm(g0), fg = sigm(g1), gg = tanh_(g2), og = sigm(g3);
    c = fg * c + ig * gg;
    float hn = og * tanh_(c);

    // ---- packed coherent h store (write-through to L3 coherence point)
    {
      unsigned hb = (unsigned)__builtin_bit_cast(unsigned short, (_Float16)hn);
      unsigned nb = (unsigned)__shfl_xor((int)hb, 1, 64);  // partner unit pu^1
      if ((pu & 1) == 0) {
        unsigned packed = hb | (nb << 16);  // little-endian: pu low, pu+1 high
        __hip_atomic_store((unsigned*)(Hn + (size_t)pb * 512 + blk * 8 + pu),
                           packed, __ATOMIC_RELAXED, __HIP_MEMORY_SCOPE_AGENT);
      }
    }
    if (t == 511) {  // plain stores; kernel-end flush makes them visible
      out[pb * 512 + jglob] = hn;
      out[32768 + pb * 512 + jglob] = c;
    }

    // ---- fence-free counter barrier (skip after last local step)
    if (tl != Tc - 1) {
      asm volatile("s_waitcnt vmcnt(0)" ::: "memory");  // h stores acked at L3
      __syncthreads();
      if (tid == 0) {
        __hip_atomic_fetch_add(cnt, 1u, __ATOMIC_RELAXED,
                               __HIP_MEMORY_SCOPE_AGENT);
        while (__hip_atomic_load(cnt, __ATOMIC_RELAXED,
                                 __HIP_MEMORY_SCOPE_AGENT) <
               64u * (unsigned)(tl + 1)) {
          __builtin_amdgcn_s_sleep(1);
        }
      }
      __syncthreads();
    }
  }
  cstate[pb * 512 + jglob] = c;
}

// ---------------------------------------------------------------------------
// Fallback: all-f32 straight from inputs (only if ws_size is tiny).
// ---------------------------------------------------------------------------
__global__ __launch_bounds__(512, 1) void naive_kernel(
    const int* __restrict__ seq, const float* __restrict__ emb,
    const float* __restrict__ W_ih, const float* __restrict__ W_hh,
    const float* __restrict__ b_ih, const float* __restrict__ b_hh,
    float* __restrict__ out) {
  __shared__ float hl[512];
  const int b = blockIdx.x, j = threadIdx.x;
  hl[j] = 0.f;
  float c = 0.f;
  __syncthreads();
  for (int t = 0; t < 512; ++t) {
    int tok = seq[b * 512 + t];
    float A[4];
#pragma unroll
    for (int g = 0; g < 4; ++g) A[g] = b_ih[g * 512 + j] + b_hh[g * 512 + j];
    for (int k = 0; k < 256; ++k) {
      float e = emb[(size_t)tok * 256 + k];
#pragma unroll
      for (int g = 0; g < 4; ++g) A[g] += e * W_ih[(size_t)(g * 512 + j) * 256 + k];
    }
    for (int k = 0; k < 512; ++k) {
      float h = hl[k];
#pragma unroll
      for (int g = 0; g < 4; ++g) A[g] += h * W_hh[(size_t)(g * 512 + j) * 512 + k];
    }
    __syncthreads();
    float ig = sigm(A[0]), fg = sigm(A[1]), gg = tanh_(A[2]), og = sigm(A[3]);
    c = fg * c + ig * gg;
    float hn = og * tanh_(c);
    hl[j] = hn;
    __syncthreads();
    if (t == 511) {
      out[b * 512 + j] = hn;
      out[32768 + b * 512 + j] = c;
    }
  }
}

// ---------------------------------------------------------------------------
extern "C" void kernel_launch(void* const* d_in, const int* in_sizes, int n_in,
                              void* d_out, int out_size, void* d_ws, size_t ws_size,
                              hipStream_t stream) {
  const int* seq = (const int*)d_in[0];
  const float* emb = (const float*)d_in[1];
  const float* W_ih = (const float*)d_in[2];
  const float* W_hh = (const float*)d_in[3];
  const float* b_ih = (const float*)d_in[4];
  const float* b_hh = (const float*)d_in[5];
  float* out = (float*)d_out;

  // workspace layout
  char* w = (char*)d_ws;
  _Float16* Wd = (_Float16*)(w + 0);            // 2,097,152 B
  _Float16* Wip = (_Float16*)(w + 2097152);     // 1,048,576 B
  float* bsum = (float*)(w + 3145728);          //     8,192 B
  _Float16* H0 = (_Float16*)(w + 3153920);      //    65,536 B
  _Float16* H1 = (_Float16*)(w + 3219456);      //    65,536 B
  float* cstate = (float*)(w + 3284992);        //   131,072 B
  unsigned* cnt = (unsigned*)(w + 3416064);     //       256 B (64 slots)
  _Float16* xgbuf = (_Float16*)(w + 3416320);   // Tc*262,144 B
  const size_t base = 3416320;

  int Tc = 0;
  const int cands[7] = {512, 256, 128, 64, 32, 16, 8};
  for (int ci = 0; ci < 7; ++ci) {
    if (base + (size_t)cands[ci] * 262144 <= ws_size) { Tc = cands[ci]; break; }
  }

  if (Tc == 0) {
    naive_kernel<<<64, 512, 0, stream>>>(seq, emb, W_ih, W_hh, b_ih, b_hh, out);
    return;
  }

  prep_kernel<<<1024, 256, 0, stream>>>(W_hh, W_ih, b_ih, b_hh, Wd, Wip, bsum,
                                        H0, cstate, cnt);
  for (int t0 = 0; t0 < 512; t0 += Tc) {
    xg_kernel<<<8 * Tc, 512, 0, stream>>>(seq, emb, Wip, bsum, xgbuf, t0, Tc);
    rec2_kernel<<<64, 512, 0, stream>>>(xgbuf, Wd, H0, H1, cstate,
                                        cnt + (t0 / Tc), out, t0, Tc);
  }
}